// Round 9
// baseline (468.749 us; speedup 1.0000x reference)
//
#include <hip/hip_runtime.h>

// GAT node regressor: 3 GAT layers (HID=64, 4 heads x 16) + linear head.
// CSR-by-dst built once per call via bucketed counting sort. Per layer:
//   k_gemm: xh = h@W; h tile in LDS, W read via VMEM (L1-resident: same 16-32KB
//           for every block) -> DS pipe only carries h (was DS-issue-bound with
//           both in LDS); unroll capped so W isn't register-hoisted (VGPR=256
//           trap). Fused al_s/al_d head reductions.
//   k_edge: per-edge softmax numerators pe[j][h] (coalesced, edge-parallel)
//   k_agg : wave-per-dst-node gather (R7-proven): chunk stash of (u, pe4) in
//           head-transposed LDS, broadcast b128 pair + 4 row gathers per group.
//           Layer 2 fuses h@out_w via shuffle.

#define NBMAX 512   // max dst buckets (dst>>8); N=100K -> 391
#define SCHUNK 4096 // edges per k_bscatter block
#define BCAP 8192   // per-bucket LDS src capacity in k_bfinal (avg 4096)

__global__ __launch_bounds__(256) void k_zero(int* p, int n) {
    int i = blockIdx.x * 256 + threadIdx.x;
    if (i < n) p[i] = 0;
}

__global__ __launch_bounds__(256) void k_bhist(const int* __restrict__ dst, int* __restrict__ bhist, int e) {
    __shared__ unsigned int h[NBMAX];
    int t = threadIdx.x;
    h[t] = 0;
    h[t + 256] = 0;
    __syncthreads();
    for (int i = blockIdx.x * 256 + t; i < e; i += gridDim.x * 256)
        atomicAdd(&h[dst[i] >> 8], 1u);
    __syncthreads();
    if (h[t]) atomicAdd(&bhist[t], (int)h[t]);
    if (h[t + 256]) atomicAdd(&bhist[t + 256], (int)h[t + 256]);
}

__global__ __launch_bounds__(512) void k_bscan(const int* __restrict__ bhist, int* __restrict__ boffs,
                                               int* __restrict__ bfill, int nb, int e) {
    __shared__ int s[NBMAX];
    int t = threadIdx.x;
    int v = (t < nb) ? bhist[t] : 0;
    s[t] = v;
    __syncthreads();
    for (int o = 1; o < 512; o <<= 1) {
        int add = (t >= o) ? s[t - o] : 0;
        __syncthreads();
        s[t] += add;
        __syncthreads();
    }
    boffs[t] = s[t] - v;  // exclusive
    if (t == 511) boffs[512] = s[511];
    bfill[t] = 0;
}

// Block-local counting sort of a 4096-edge chunk by dst>>8, then streamed
// writes of sorted runs. Packs src (17b) | (dst&255)<<24 into 4B.
__global__ __launch_bounds__(512) void k_bscatter(const int* __restrict__ src, const int* __restrict__ dst,
                                                  const int* __restrict__ boffs, int* __restrict__ bfill,
                                                  unsigned int* __restrict__ edata, int e) {
    __shared__ unsigned int hist[NBMAX];   // counts, then cursor
    __shared__ unsigned int loc[NBMAX];    // local exclusive offsets
    __shared__ int gbase[NBMAX];
    __shared__ unsigned int stmp[NBMAX];
    __shared__ unsigned int sortbuf[SCHUNK];
    __shared__ int posbuf[SCHUNK];
    int t = threadIdx.x;
    int i0 = blockIdx.x * SCHUNK;
    int cnt = min(SCHUNK, e - i0);
    hist[t] = 0;
    __syncthreads();
    for (int j = t; j < cnt; j += 512) atomicAdd(&hist[dst[i0 + j] >> 8], 1u);
    __syncthreads();
    unsigned int v = hist[t];
    stmp[t] = v;
    __syncthreads();
    for (int o = 1; o < 512; o <<= 1) {
        unsigned int add = (t >= o) ? stmp[t - o] : 0;
        __syncthreads();
        stmp[t] += add;
        __syncthreads();
    }
    loc[t] = stmp[t] - v;
    int gb = 0;
    if (v > 0) gb = atomicAdd(&bfill[t], (int)v);  // reserve contiguous run in bucket t
    gbase[t] = boffs[t] + gb - (int)loc[t];
    hist[t] = loc[t];  // cursor
    __syncthreads();
    for (int j = t; j < cnt; j += 512) {
        int d = dst[i0 + j];
        int s = src[i0 + j];
        int b = d >> 8;
        unsigned int p = atomicAdd(&hist[b], 1u);
        sortbuf[p] = (unsigned int)s | ((unsigned int)(d & 255) << 24);
        posbuf[p] = gbase[b] + (int)p;
    }
    __syncthreads();
    for (int j = t; j < cnt; j += 512) edata[posbuf[j]] = sortbuf[j];
}

// One block per bucket: 256-bin counting sort by local dst; coalesced output
// of offs, ssrc (sorted srcs) and sdst (sorted dsts, for k_edge).
__global__ __launch_bounds__(256) void k_bfinal(const unsigned int* __restrict__ edata,
                                                const int* __restrict__ boffs, int* __restrict__ offs,
                                                int* __restrict__ ssrc, int* __restrict__ sdst,
                                                int n, int nb) {
    __shared__ unsigned int hist[256];
    __shared__ unsigned int stmp[256];
    __shared__ unsigned int loc[256];
    __shared__ unsigned int srcbuf[BCAP];
    __shared__ unsigned char dstbuf[BCAP];
    int b = blockIdx.x;
    int t = threadIdx.x;
    int e0 = boffs[b], e1 = boffs[b + 1];
    int cnt = e1 - e0;
    hist[t] = 0;
    __syncthreads();
    for (int j = t; j < cnt; j += 256) atomicAdd(&hist[edata[e0 + j] >> 24], 1u);
    __syncthreads();
    unsigned int v = hist[t];
    stmp[t] = v;
    __syncthreads();
    for (int o = 1; o < 256; o <<= 1) {
        unsigned int add = (t >= o) ? stmp[t - o] : 0;
        __syncthreads();
        stmp[t] += add;
        __syncthreads();
    }
    loc[t] = stmp[t] - v;
    int node = b * 256 + t;
    if (node < n) offs[node] = e0 + (int)loc[t];
    if (b == nb - 1 && t == 0) offs[n] = e1;
    hist[t] = loc[t];  // cursor
    __syncthreads();
    if (cnt <= BCAP) {
        for (int j = t; j < cnt; j += 256) {
            unsigned int p = edata[e0 + j];
            unsigned int pos = atomicAdd(&hist[p >> 24], 1u);
            srcbuf[pos] = p & 0xFFFFFFu;
            dstbuf[pos] = (unsigned char)(p >> 24);
        }
        __syncthreads();
        for (int j = t; j < cnt; j += 256) {
            ssrc[e0 + j] = (int)srcbuf[j];
            sdst[e0 + j] = b * 256 + (int)dstbuf[j];
        }
    } else {  // safety fallback (never hit for Poisson(4096) buckets)
        for (int j = t; j < cnt; j += 256) {
            unsigned int p = edata[e0 + j];
            unsigned int pos = atomicAdd(&hist[p >> 24], 1u);
            ssrc[e0 + (int)pos] = (int)(p & 0xFFFFFFu);
            sdst[e0 + (int)pos] = b * 256 + (int)(p >> 24);
        }
    }
}

// xh = h @ W  (h: [n, D_IN], W: [D_IN, 64]) fused with per-head attention
// logits. 64-node tile; thread (cg,ng) computes 4 nodes x 4 cols.
// h tile in LDS; W read from global each k-quad (L1-resident: every block
// reads the same 16-32KB). unroll capped: full unroll hoists all W into
// 256 VGPRs (9% occupancy trap, measured R6).
template <int D_IN>
__global__ __launch_bounds__(256) void k_gemm(const float* __restrict__ h, const float* __restrict__ W,
                                              const float* __restrict__ asrc, const float* __restrict__ adst,
                                              float* __restrict__ xh, float* __restrict__ als,
                                              float* __restrict__ ald, int n) {
    constexpr int HSTR = D_IN + 4;
    __shared__ float hlds[64 * HSTR];
    int t = threadIdx.x;
    int node0 = blockIdx.x * 64;
    constexpr int HTOT = 64 * D_IN / 4;
    for (int i = t; i < HTOT; i += 256) {
        int f = i * 4;
        int nd = f / D_IN, k = f % D_IN;
        float4 val = make_float4(0.f, 0.f, 0.f, 0.f);
        if (node0 + nd < n) val = *(const float4*)(h + (size_t)(node0 + nd) * D_IN + k);
        *(float4*)(hlds + nd * HSTR + k) = val;
    }
    __syncthreads();
    int cg = t & 15, ng = t >> 4;
    float4 acc[4];
#pragma unroll
    for (int i = 0; i < 4; ++i) acc[i] = make_float4(0.f, 0.f, 0.f, 0.f);
#pragma unroll 2
    for (int k = 0; k < D_IN; k += 4) {
        float4 w0 = *(const float4*)(W + (size_t)(k + 0) * 64 + cg * 4);  // L1 hit
        float4 w1 = *(const float4*)(W + (size_t)(k + 1) * 64 + cg * 4);
        float4 w2 = *(const float4*)(W + (size_t)(k + 2) * 64 + cg * 4);
        float4 w3 = *(const float4*)(W + (size_t)(k + 3) * 64 + cg * 4);
#pragma unroll
        for (int i = 0; i < 4; ++i) {
            float4 hv = *(const float4*)(hlds + (ng * 4 + i) * HSTR + k);
            acc[i].x += hv.x * w0.x + hv.y * w1.x + hv.z * w2.x + hv.w * w3.x;
            acc[i].y += hv.x * w0.y + hv.y * w1.y + hv.z * w2.y + hv.w * w3.y;
            acc[i].z += hv.x * w0.z + hv.y * w1.z + hv.z * w2.z + hv.w * w3.z;
            acc[i].w += hv.x * w0.w + hv.y * w1.w + hv.z * w2.w + hv.w * w3.w;
        }
    }
    float4 as4 = *(const float4*)(asrc + cg * 4);
    float4 ad4 = *(const float4*)(adst + cg * 4);
#pragma unroll
    for (int i = 0; i < 4; ++i) {
        int node = node0 + ng * 4 + i;
        float ps = acc[i].x * as4.x + acc[i].y * as4.y + acc[i].z * as4.z + acc[i].w * as4.w;
        float pd = acc[i].x * ad4.x + acc[i].y * ad4.y + acc[i].z * ad4.z + acc[i].w * ad4.w;
        ps += __shfl_xor(ps, 1, 64);
        ps += __shfl_xor(ps, 2, 64);
        pd += __shfl_xor(pd, 1, 64);
        pd += __shfl_xor(pd, 2, 64);
        if (node < n) {
            *(float4*)(xh + (size_t)node * 64 + cg * 4) = acc[i];
            if ((cg & 3) == 0) {
                als[node * 4 + (cg >> 2)] = ps;
                ald[node * 4 + (cg >> 2)] = pd;
            }
        }
    }
}

__device__ inline float4 lrelu4(float4 v) {
    float4 r;
    r.x = v.x >= 0.f ? v.x : 0.2f * v.x;
    r.y = v.y >= 0.f ? v.y : 0.2f * v.y;
    r.z = v.z >= 0.f ? v.z : 0.2f * v.z;
    r.w = v.w >= 0.f ? v.w : 0.2f * v.w;
    return r;
}

// Edge-parallel softmax numerators: pe[j][h] = exp(lrelu(als[u]+ald[d]) - m[d]),
// m[d] = lrelu(als[d]+ald[d]) (self-logit as per-head shift; single pass,
// algebraically identical to ref's max-subtraction).
__global__ __launch_bounds__(256) void k_edge(const int* __restrict__ ssrc, const int* __restrict__ sdst,
                                              const float* __restrict__ als, const float* __restrict__ ald,
                                              float* __restrict__ pei, int e) {
    int j = blockIdx.x * 256 + threadIdx.x;
    if (j >= e) return;
    int u = ssrc[j], d = sdst[j];
    float4 alu = *(const float4*)(als + 4 * (size_t)u);
    float4 asd = *(const float4*)(als + 4 * (size_t)d);
    float4 add4 = *(const float4*)(ald + 4 * (size_t)d);
    float4 m4 = lrelu4(make_float4(asd.x + add4.x, asd.y + add4.y, asd.z + add4.z, asd.w + add4.w));
    float4 e4 = lrelu4(make_float4(alu.x + add4.x, alu.y + add4.y, alu.z + add4.z, alu.w + add4.w));
    float4 pe;
    pe.x = __expf(e4.x - m4.x);
    pe.y = __expf(e4.y - m4.y);
    pe.z = __expf(e4.z - m4.z);
    pe.w = __expf(e4.w - m4.w);
    *(float4*)(pei + 4 * (size_t)j) = pe;
}

// One wave per destination node; lane = feature column (head = lane>>4).
// Chunk phase: lane=edge loads (u, pe4) coalesced; stash u as row BYTE offset
// and pe transposed [head][edge] in LDS (all 64 lanes write; pad u=v, pe=0).
// Accumulate: per 4 edges, 2x broadcast ds_read_b128 + 4 row gathers + fmacs;
// z accumulated redundantly per lane (no end shuffle-reduce).
__global__ __launch_bounds__(256) void k_agg(const float* __restrict__ xh, const float* __restrict__ pei,
                                             const int* __restrict__ offs, const int* __restrict__ ssrc,
                                             const float* __restrict__ bias, float* __restrict__ hout,
                                             const float* __restrict__ outw, const float* __restrict__ outb,
                                             float* __restrict__ fout, int n) {
    __shared__ int s_u[4][64];
    __shared__ float s_pe[4][4][64];  // [wslot][head][edge]
    int wslot = threadIdx.x >> 6;
    int lane = threadIdx.x & 63;
    int v = (blockIdx.x * 256 + threadIdx.x) >> 6;
    if (v >= n) return;
    int head = lane >> 4;
    int* ub = s_u[wslot];
    float* per = s_pe[wslot][head];      // read row for my head
    float* pew = &s_pe[wslot][0][lane];  // write base, stride 64 per head

    int start = offs[v], end = offs[v + 1];
    const char* xl = (const char*)(xh + lane);      // lane column folded into base
    float acc = *(const float*)(xl + ((size_t)(unsigned)v << 8));  // self, pe=1
    float zsum = 0.f;

    for (int s0 = start; s0 < end; s0 += 64) {
        int cnt = min(64, end - s0);
        bool act = lane < cnt;
        int u = v;
        float4 pe = make_float4(0.f, 0.f, 0.f, 0.f);
        if (act) {
            u = ssrc[s0 + lane];
            pe = *(const float4*)(pei + 4 * (size_t)(s0 + lane));
        }
        ub[lane] = u << 8;   // row byte offset; pad lanes point at v (pe=0)
        pew[0] = pe.x;       // transposed stash: bank stride 64 -> 2-way, free
        pew[64] = pe.y;
        pew[128] = pe.z;
        pew[192] = pe.w;
        // same-wave LDS RAW (in-order DS unit), no barrier needed
        int ng = (cnt + 3) >> 2;
        int g = 0;
        for (; g + 2 <= ng; g += 2) {
            int4 uu0 = *(const int4*)&ub[g * 4];
            int4 uu1 = *(const int4*)&ub[g * 4 + 4];
            float4 pp0 = *(const float4*)&per[g * 4];
            float4 pp1 = *(const float4*)&per[g * 4 + 4];
            float x0 = *(const float*)(xl + (size_t)(unsigned)uu0.x);
            float x1 = *(const float*)(xl + (size_t)(unsigned)uu0.y);
            float x2 = *(const float*)(xl + (size_t)(unsigned)uu0.z);
            float x3 = *(const float*)(xl + (size_t)(unsigned)uu0.w);
            float x4 = *(const float*)(xl + (size_t)(unsigned)uu1.x);
            float x5 = *(const float*)(xl + (size_t)(unsigned)uu1.y);
            float x6 = *(const float*)(xl + (size_t)(unsigned)uu1.z);
            float x7 = *(const float*)(xl + (size_t)(unsigned)uu1.w);
            zsum += pp0.x + pp0.y + pp0.z + pp0.w;
            zsum += pp1.x + pp1.y + pp1.z + pp1.w;
            acc += pp0.x * x0; acc += pp0.y * x1; acc += pp0.z * x2; acc += pp0.w * x3;
            acc += pp1.x * x4; acc += pp1.y * x5; acc += pp1.z * x6; acc += pp1.w * x7;
        }
        for (; g < ng; ++g) {
            int4 uu = *(const int4*)&ub[g * 4];
            float4 pp = *(const float4*)&per[g * 4];
            float x0 = *(const float*)(xl + (size_t)(unsigned)uu.x);
            float x1 = *(const float*)(xl + (size_t)(unsigned)uu.y);
            float x2 = *(const float*)(xl + (size_t)(unsigned)uu.z);
            float x3 = *(const float*)(xl + (size_t)(unsigned)uu.w);
            zsum += pp.x + pp.y + pp.z + pp.w;
            acc += pp.x * x0; acc += pp.y * x1; acc += pp.z * x2; acc += pp.w * x3;
        }
    }
    float z = 1.f + zsum;  // +1 = self edge
    float o = acc / (z + 1e-16f) + bias[lane];
    o = fmaxf(o, 0.f);
    if (outw) {
        float tsum = o * outw[lane];
#pragma unroll
        for (int d = 32; d; d >>= 1) tsum += __shfl_down(tsum, d, 64);
        if (lane == 0) fout[v] = tsum + outb[0];
    } else {
        hout[((size_t)v << 6) + lane] = o;
    }
}

extern "C" void kernel_launch(void* const* d_in, const int* in_sizes, int n_in,
                              void* d_out, int out_size, void* d_ws, size_t ws_size,
                              hipStream_t stream) {
    const float* x = (const float*)d_in[0];
    const int* ei = (const int*)d_in[1];
    const float* w[3] = {(const float*)d_in[2], (const float*)d_in[6], (const float*)d_in[10]};
    const float* as[3] = {(const float*)d_in[3], (const float*)d_in[7], (const float*)d_in[11]};
    const float* ad[3] = {(const float*)d_in[4], (const float*)d_in[8], (const float*)d_in[12]};
    const float* b[3] = {(const float*)d_in[5], (const float*)d_in[9], (const float*)d_in[13]};
    const float* outw = (const float*)d_in[14];
    const float* outb = (const float*)d_in[15];

    const int N = in_sizes[0] / 128;
    const int E = in_sizes[1] / 2;
    const int* src = ei;
    const int* dst = ei + E;
    const int NB = (N + 255) / 256;  // 391 <= NBMAX

    char* ws = (char*)d_ws;
    auto alloc = [&](size_t bytes) -> void* {
        void* p = (void*)ws;
        ws += (bytes + 255) & ~(size_t)255;
        return p;
    };
    int* bhist = (int*)alloc(NBMAX * 4);
    int* boffs = (int*)alloc((NBMAX + 1) * 4);
    int* bfill = (int*)alloc(NBMAX * 4);
    int* offs = (int*)alloc((size_t)(N + 1) * 4);
    int* ssrc = (int*)alloc((size_t)E * 4);
    int* sdst = (int*)alloc((size_t)E * 4);
    float* pei = (float*)alloc((size_t)E * 4 * 4);
    float* xh = (float*)alloc((size_t)N * 64 * 4);
    float* hbuf = (float*)alloc((size_t)N * 64 * 4);
    float* als = (float*)alloc((size_t)N * 4 * 4);
    float* ald = (float*)alloc((size_t)N * 4 * 4);
    // edata (E*4B) aliases xh (N*256B): dead before the first k_gemm writes xh.
    unsigned int* edata = (unsigned int*)xh;

    k_zero<<<(NBMAX + 255) / 256, 256, 0, stream>>>(bhist, NBMAX);
    k_bhist<<<256, 256, 0, stream>>>(dst, bhist, E);
    k_bscan<<<1, 512, 0, stream>>>(bhist, boffs, bfill, NB, E);
    k_bscatter<<<(E + SCHUNK - 1) / SCHUNK, 512, 0, stream>>>(src, dst, boffs, bfill, edata, E);
    k_bfinal<<<NB, 256, 0, stream>>>(edata, boffs, offs, ssrc, sdst, N, NB);

    const int gblocks = (N + 63) / 64;
    const int ablocks = (N + 3) / 4;
    const int eblocks = (E + 255) / 256;

    k_gemm<128><<<gblocks, 256, 0, stream>>>(x, w[0], as[0], ad[0], xh, als, ald, N);
    k_edge<<<eblocks, 256, 0, stream>>>(ssrc, sdst, als, ald, pei, E);
    k_agg<<<ablocks, 256, 0, stream>>>(xh, pei, offs, ssrc, b[0], hbuf, nullptr, nullptr, nullptr, N);
    k_gemm<64><<<gblocks, 256, 0, stream>>>(hbuf, w[1], as[1], ad[1], xh, als, ald, N);
    k_edge<<<eblocks, 256, 0, stream>>>(ssrc, sdst, als, ald, pei, E);
    k_agg<<<ablocks, 256, 0, stream>>>(xh, pei, offs, ssrc, b[1], hbuf, nullptr, nullptr, nullptr, N);
    k_gemm<64><<<gblocks, 256, 0, stream>>>(hbuf, w[2], as[2], ad[2], xh, als, ald, N);
    k_edge<<<eblocks, 256, 0, stream>>>(ssrc, sdst, als, ald, pei, E);
    k_agg<<<ablocks, 256, 0, stream>>>(xh, pei, offs, ssrc, b[2], nullptr, outw, outb, (float*)d_out, N);
}